// Round 1
// 178.401 us; speedup vs baseline: 1.5257x; 1.5257x over previous
//
#include <hip/hip_runtime.h>

#define NN 4096
#define NE 131072
#define TIN 136
#define HD1 68
#define HD2 34
#define TD 128

__device__ __forceinline__ void add4(float4& a, const float4& b) {
    a.x += b.x; a.y += b.y; a.z += b.z; a.w += b.w;
}

// ---------------- CSR build ----------------

// cnt[0..NN) = in-degree by tgt, cnt[NN..2NN) = out-degree by src
// block 0 also zeroes the pad row (index NN) of hs/ta/tb used by k_step.
__global__ void k_count(const int* __restrict__ ei, int* cnt,
                        float2* hsP, float2* taP, float2* tbP) {
    int e = blockIdx.x * 256 + threadIdx.x;   // grid = NE/256 exactly
    int s = ei[e], t = ei[NE + e];
    atomicAdd(&cnt[t], 1);
    atomicAdd(&cnt[NN + s], 1);
    if (blockIdx.x == 0) {
        int tid = threadIdx.x;
        float2 z = make_float2(0.f, 0.f);
        if (tid < 64)       hsP[NN * 64 + tid] = z;
        else if (tid < 128) taP[NN * 64 + (tid - 64)] = z;
        else if (tid < 192) tbP[NN * 64 + (tid - 128)] = z;
    }
}

// two independent exclusive scans of NN ints; block 0 -> tgt, block 1 -> src
__global__ void k_scan2(const int* __restrict__ cnt, int* off, int* cur) {
    const int* c = cnt + blockIdx.x * NN;
    int* of = off + blockIdx.x * (NN + 1);
    int* cu = cur + blockIdx.x * NN;
    __shared__ int part[256];
    int tid = threadIdx.x;
    int base = tid * 16;
    int loc[16];
    int s = 0;
    for (int j = 0; j < 16; ++j) { loc[j] = s; s += c[base + j]; }
    part[tid] = s;
    __syncthreads();
    if (tid == 0) {
        int acc = 0;
        for (int i = 0; i < 256; ++i) { int v = part[i]; part[i] = acc; acc += v; }
    }
    __syncthreads();
    int b = part[tid];
    for (int j = 0; j < 16; ++j) { int v = b + loc[j]; of[base + j] = v; cu[base + j] = v; }
    if (tid == 255) of[NN] = b + s;
}

__global__ void k_fill(const int* __restrict__ ei, int* cur,
                       unsigned short* csrT, unsigned short* csrS) {
    int e = blockIdx.x * 256 + threadIdx.x;
    int s = ei[e], t = ei[NE + e];
    int p = atomicAdd(&cur[t], 1);
    csrT[p] = (unsigned short)s;   // in-neighbor (source) list of t
    int q = atomicAdd(&cur[NN + s], 1);
    csrS[q] = (unsigned short)t;   // out-neighbor (target) list of s
}

// ---------------- SAGE layer 1: concat + mean + linear, block per node ----

__global__ __launch_bounds__(256) void k_sage1(
        const float* __restrict__ x, const float* __restrict__ pos,
        const int* __restrict__ off_tgt, const unsigned short* __restrict__ csrT,
        const float* __restrict__ W1l, const float* __restrict__ b1v,
        const float* __restrict__ W1r, float* __restrict__ h1) {
    __shared__ float xr[TIN], mr[TIN];
    int i = blockIdx.x;
    int t = threadIdx.x;
    int bgn = off_tgt[i], end = off_tgt[i + 1];
    if (t < TIN) {
        const float* src;
        int str;
        if (t < 128) { src = x + t; str = 128; }
        else         { src = pos + (t - 128); str = 8; }
        xr[t] = src[i * str];
        // unroll-4 gather: 4 independent loads in flight
        float a0 = 0.f, a1 = 0.f, a2 = 0.f, a3 = 0.f;
        int p = bgn;
        for (; p + 4 <= end; p += 4) {
            int j0 = csrT[p], j1 = csrT[p + 1], j2 = csrT[p + 2], j3 = csrT[p + 3];
            a0 += src[j0 * str];
            a1 += src[j1 * str];
            a2 += src[j2 * str];
            a3 += src[j3 * str];
        }
        for (; p < end; ++p) a0 += src[(int)csrT[p] * str];
        int d = end - bgn;
        mr[t] = ((a0 + a1) + (a2 + a3)) / (float)(d > 0 ? d : 1);
    }
    __syncthreads();
    if (t < HD1) {
        const float* wl = W1l + t * TIN;
        const float* wr = W1r + t * TIN;
        float acc = b1v[t];
        for (int k = 0; k < TIN; ++k) acc += wl[k] * mr[k] + wr[k] * xr[k];
        h1[i * HD1 + t] = fmaxf(acc, 0.f);
    }
}

// --- SAGE2 + angle + cos/sin + Ox + W-GEMM + hsync, wave per node (4/block) ---
// W staged once per block into LDS as swizzled transpose (Wt[k][f^ (k&30)]):
// keeps (f0,f0+1) pairs 8B-adjacent for ds_read_b64 and spreads banks.

__global__ __launch_bounds__(256) void k_sage2hs(
        const float* __restrict__ h1,
        const int* __restrict__ off_tgt, const unsigned short* __restrict__ csrT,
        const float* __restrict__ W2l, const float* __restrict__ b2v,
        const float* __restrict__ W2r,
        const float* __restrict__ Wa, const float* __restrict__ ba,
        const float* __restrict__ x, const float* __restrict__ W,
        const float* __restrict__ bias,
        float2* __restrict__ cs, float2* __restrict__ hs) {
    __shared__ float lm[4][HD1], lh[4][HD1];
    __shared__ float ox[4][TD];
    __shared__ float Wt[TD * TD];   // 64 KB swizzled transpose of W
    int w = threadIdx.x >> 6, l = threadIdx.x & 63;
    int i = blockIdx.x * 4 + w;

    // --- stage W -> LDS (coalesced float4 global reads, swizzled writes) ---
    {
        const float4* W4 = (const float4*)W;
        int t = threadIdx.x;
        #pragma unroll 4
        for (int r = 0; r < 16; ++r) {
            int v = r * 256 + t;
            float4 wv = W4[v];
            int m = v * 4;
            int f = m >> 7;
            int k0 = m & 127;
            Wt[(k0    ) * TD + (f ^ ((k0    ) & 30))] = wv.x;
            Wt[(k0 + 1) * TD + (f ^ ((k0 + 1) & 30))] = wv.y;
            Wt[(k0 + 2) * TD + (f ^ ((k0 + 2) & 30))] = wv.z;
            Wt[(k0 + 3) * TD + (f ^ ((k0 + 3) & 30))] = wv.w;
        }
    }

    // --- gather (unroll 4; features l and 64+(l&3) fused in one chain) ---
    int bgn = off_tgt[i], end = off_tgt[i + 1];
    int d = end - bgn;
    float inv = 1.f / (float)(d > 0 ? d : 1);
    int fx = 64 + (l & 3);
    float s0 = 0.f, s1 = 0.f, s2 = 0.f, s3 = 0.f;
    float e0 = 0.f, e1 = 0.f, e2 = 0.f, e3 = 0.f;
    int p = bgn;
    for (; p + 4 <= end; p += 4) {
        int j0 = csrT[p], j1 = csrT[p + 1], j2 = csrT[p + 2], j3 = csrT[p + 3];
        s0 += h1[j0 * HD1 + l];  e0 += h1[j0 * HD1 + fx];
        s1 += h1[j1 * HD1 + l];  e1 += h1[j1 * HD1 + fx];
        s2 += h1[j2 * HD1 + l];  e2 += h1[j2 * HD1 + fx];
        s3 += h1[j3 * HD1 + l];  e3 += h1[j3 * HD1 + fx];
    }
    for (; p < end; ++p) {
        int j0 = csrT[p];
        s0 += h1[j0 * HD1 + l];  e0 += h1[j0 * HD1 + fx];
    }
    lm[w][l] = ((s0 + s1) + (s2 + s3)) * inv;
    lh[w][l] = h1[i * HD1 + l];
    if (l < 4) {
        lm[w][64 + l] = ((e0 + e1) + (e2 + e3)) * inv;
        lh[w][64 + l] = h1[i * HD1 + 64 + l];
    }
    __syncthreads();

    float v = 0.f;
    if (l < HD2) {
        const float* wl = W2l + l * HD1;
        const float* wr = W2r + l * HD1;
        float acc = b2v[l];
        for (int k = 0; k < HD1; ++k) acc += wl[k] * lm[w][k] + wr[k] * lh[w][k];
        v = Wa[l] * fmaxf(acc, 0.f);
    }
    // butterfly: all 64 lanes end with the full sum
    for (int off = 32; off >= 1; off >>= 1) v += __shfl_xor(v, off);
    float ang = v + ba[0];
    float c = cosf(ang), s = sinf(ang);
    if (l == 0) cs[i] = make_float2(c, s);

    // phase 2: lane l owns column pair (2l, 2l+1)
    int f0 = 2 * l, f1 = f0 + 1;
    float2 xv = *(const float2*)&x[i * TD + f0];
    ox[w][f0] = c * xv.x - s * xv.y;
    ox[w][f1] = s * xv.x + c * xv.y;
    __syncthreads();

    // GEMM from LDS: per 2 k's -> 2 ds_read_b64 (W pair) + 1 ds_read_b64 (ox)
    float a0 = 0.f, a1 = 0.f;
    #pragma unroll 4
    for (int k = 0; k < TD; k += 2) {
        int sw = k & 30;   // same for k and k+1 (k even)
        float2 o2 = *(const float2*)&ox[w][k];
        float2 wA = *(const float2*)&Wt[k * TD + (f0 ^ sw)];
        float2 wB = *(const float2*)&Wt[(k + 1) * TD + (f0 ^ sw)];
        a0 += wA.x * o2.x + wB.x * o2.y;
        a1 += wA.y * o2.x + wB.y * o2.y;
    }
    float t0 = c * a0 + s * a1 + bias[f0];
    float t1 = -s * a0 + c * a1 + bias[f1];
    float u0 = c * t0 - s * t1;
    float u1 = s * t0 + c * t1;
    hs[i * 64 + l] = make_float2(u0, u1);
}

// ---- one Taylor step: wave = node row; half-wave = neighbor parity --------
// lanes 0-31 accumulate even neighbors, 32-63 odd; each lane owns a float4
// (columns 4c..4c+3). Index NN is a zero row so the inner loop runs in
// static groups of 4 pair-iterations (8 loads in flight) with no tail checks.
// MODE: 1 = first step (init res), 0 = middle, 2 = last (fuse O^T + relu)

template <int MODE>
__global__ __launch_bounds__(256) void k_step(
        const float4* __restrict__ tin, float4* __restrict__ tout,
        float4* __restrict__ res, const int* __restrict__ off_src,
        const unsigned short* __restrict__ csrS, float scale,
        const float2* __restrict__ cs, float4* __restrict__ outv) {
    int idx = blockIdx.x * 256 + threadIdx.x;
    int i = idx >> 6;          // node (wave-uniform)
    int l = idx & 63;
    int c32 = l & 31;          // float4 column block
    int hi = l >> 5;           // neighbor parity
    int bgn = off_src[i], end = off_src[i + 1];
    int d = end - bgn;
    float dinv = d > 0 ? 1.f / (float)d : 0.f;
    float4 u = tin[i * 32 + c32];
    float4 acc0 = make_float4(0.f, 0.f, 0.f, 0.f);
    float4 acc1 = make_float4(0.f, 0.f, 0.f, 0.f);
    for (int base = bgn; base < end; base += 64) {
        int m = end - base;
        if (m > 64) m = 64;
        int jj = (l < m) ? (int)csrS[base + l] : NN;   // pad -> zero row
        int pr = ((m + 1) >> 1);
        pr = (pr + 3) & ~3;                            // round to unroll-4
        for (int q = 0; q < pr; q += 4) {
            int j0 = __shfl(jj, 2 * q + hi);
            int j1 = __shfl(jj, 2 * q + 2 + hi);
            int j2 = __shfl(jj, 2 * q + 4 + hi);
            int j3 = __shfl(jj, 2 * q + 6 + hi);
            float4 v0 = tin[j0 * 32 + c32];
            float4 v1 = tin[j1 * 32 + c32];
            float4 v2 = tin[j2 * 32 + c32];
            float4 v3 = tin[j3 * 32 + c32];
            add4(acc0, v0);
            add4(acc1, v1);
            add4(acc0, v2);
            add4(acc1, v3);
        }
    }
    add4(acc0, acc1);
    acc0.x += __shfl_xor(acc0.x, 32);
    acc0.y += __shfl_xor(acc0.y, 32);
    acc0.z += __shfl_xor(acc0.z, 32);
    acc0.w += __shfl_xor(acc0.w, 32);
    if (hi == 0) {
        float4 nu;
        nu.x = scale * (u.x - dinv * acc0.x);
        nu.y = scale * (u.y - dinv * acc0.y);
        nu.z = scale * (u.z - dinv * acc0.z);
        nu.w = scale * (u.w - dinv * acc0.w);
        if (MODE == 1) {
            res[i * 32 + c32] = make_float4(u.x + nu.x, u.y + nu.y,
                                            u.z + nu.z, u.w + nu.w);
            tout[i * 32 + c32] = nu;
        } else if (MODE == 0) {
            float4 r = res[i * 32 + c32];
            add4(r, nu);
            res[i * 32 + c32] = r;
            tout[i * 32 + c32] = nu;
        } else {
            float4 r = res[i * 32 + c32];
            add4(r, nu);
            float2 cv = cs[i];
            float o0 =  cv.x * r.x + cv.y * r.y;
            float o1 = -cv.y * r.x + cv.x * r.y;
            float o2 =  cv.x * r.z + cv.y * r.w;
            float o3 = -cv.y * r.z + cv.x * r.w;
            outv[i * 32 + c32] = make_float4(fmaxf(o0, 0.f), fmaxf(o1, 0.f),
                                             fmaxf(o2, 0.f), fmaxf(o3, 0.f));
        }
    }
}

extern "C" void kernel_launch(void* const* d_in, const int* in_sizes, int n_in,
                              void* d_out, int out_size, void* d_ws, size_t ws_size,
                              hipStream_t stream) {
    const float* x    = (const float*)d_in[0];
    const float* pos  = (const float*)d_in[1];
    const int*   ei   = (const int*)d_in[2];
    const float* W1l  = (const float*)d_in[3];
    const float* b1   = (const float*)d_in[4];
    const float* W1r  = (const float*)d_in[5];
    const float* W2l  = (const float*)d_in[6];
    const float* b2   = (const float*)d_in[7];
    const float* W2r  = (const float*)d_in[8];
    const float* Wa   = (const float*)d_in[9];
    const float* ba   = (const float*)d_in[10];
    const float* W    = (const float*)d_in[11];
    const float* bias = (const float*)d_in[12];
    float4* out = (float4*)d_out;

    char* ws = (char*)d_ws;
    size_t o = 0;
    auto alloc = [&](size_t bytes) -> void* {
        void* p = ws + o;
        o += (bytes + 255) & ~(size_t)255;
        return p;
    };

    int* cnt  = (int*)alloc(2 * NN * 4);          // [tgt | src]
    int* off  = (int*)alloc(2 * (NN + 1) * 4);    // [off_tgt | off_src]
    int* cur  = (int*)alloc(2 * NN * 4);
    unsigned short* csrT = (unsigned short*)alloc(NE * 2);
    unsigned short* csrS = (unsigned short*)alloc(NE * 2);
    float* h1   = (float*)alloc(NN * HD1 * 4);
    float2* cs  = (float2*)alloc(NN * 8);
    float2* hs  = (float2*)alloc((NN * 64 + 64) * 8);   // +1 zero row
    float4* ta  = (float4*)alloc((NN * 64 + 64) * 8);   // +1 zero row
    float4* tb  = (float4*)alloc((NN * 64 + 64) * 8);   // +1 zero row
    float4* res = (float4*)alloc(NN * 64 * 8);

    int* off_tgt = off;
    int* off_src = off + (NN + 1);

    hipMemsetAsync(cnt, 0, 2 * NN * 4, stream);
    k_count<<<NE / 256, 256, 0, stream>>>(ei, cnt, hs, (float2*)ta, (float2*)tb);
    k_scan2<<<2, 256, 0, stream>>>(cnt, off, cur);
    k_fill<<<NE / 256, 256, 0, stream>>>(ei, cur, csrT, csrS);

    k_sage1<<<NN, 256, 0, stream>>>(x, pos, off_tgt, csrT, W1l, b1, W1r, h1);
    k_sage2hs<<<NN / 4, 256, 0, stream>>>(h1, off_tgt, csrT, W2l, b2, W2r,
                                          Wa, ba, x, W, bias, cs, hs);

    const int G = NN * 64 / 256;   // 1024 blocks
    k_step<1><<<G, 256, 0, stream>>>((const float4*)hs, ta, res, off_src, csrS, -1.f / 1.f, cs, out);
    k_step<0><<<G, 256, 0, stream>>>(ta, tb, res, off_src, csrS, -1.f / 2.f, cs, out);
    k_step<0><<<G, 256, 0, stream>>>(tb, ta, res, off_src, csrS, -1.f / 3.f, cs, out);
    k_step<0><<<G, 256, 0, stream>>>(ta, tb, res, off_src, csrS, -1.f / 4.f, cs, out);
    k_step<0><<<G, 256, 0, stream>>>(tb, ta, res, off_src, csrS, -1.f / 5.f, cs, out);
    k_step<0><<<G, 256, 0, stream>>>(ta, tb, res, off_src, csrS, -1.f / 6.f, cs, out);
    k_step<0><<<G, 256, 0, stream>>>(tb, ta, res, off_src, csrS, -1.f / 7.f, cs, out);
    k_step<2><<<G, 256, 0, stream>>>(ta, tb, res, off_src, csrS, -1.f / 8.f, cs, out);
}

// Round 2
// 166.367 us; speedup vs baseline: 1.6360x; 1.0723x over previous
//
#include <hip/hip_runtime.h>

#define NN 4096
#define NE 131072
#define TIN 136
#define HD1 68
#define HD2 34
#define TD 128

__device__ __forceinline__ void add4(float4& a, const float4& b) {
    a.x += b.x; a.y += b.y; a.z += b.z; a.w += b.w;
}

// ---------------- CSR build ----------------

// cnt[0..NN) = in-degree by tgt, cnt[NN..2NN) = out-degree by src
// block 0 also zeroes pad rows (index NN) of hs/ta/tb/yr2.
__global__ void k_count(const int* __restrict__ ei, int* cnt,
                        float2* hsP, float2* taP, float2* tbP, float4* yr2P) {
    int e = blockIdx.x * 256 + threadIdx.x;   // grid = NE/256 exactly
    int s = ei[e], t = ei[NE + e];
    atomicAdd(&cnt[t], 1);
    atomicAdd(&cnt[NN + s], 1);
    if (blockIdx.x == 0) {
        int tid = threadIdx.x;
        float2 z = make_float2(0.f, 0.f);
        if (tid < 64)       hsP[NN * 64 + tid] = z;
        else if (tid < 128) taP[NN * 64 + (tid - 64)] = z;
        else if (tid < 192) tbP[NN * 64 + (tid - 128)] = z;
        else if (tid < 210) yr2P[NN * 18 + (tid - 192)] = make_float4(0.f, 0.f, 0.f, 0.f);
    }
}

// two independent exclusive scans of NN ints; block 0 -> tgt, block 1 -> src
__global__ void k_scan2(const int* __restrict__ cnt, int* off, int* cur) {
    const int* c = cnt + blockIdx.x * NN;
    int* of = off + blockIdx.x * (NN + 1);
    int* cu = cur + blockIdx.x * NN;
    __shared__ int part[256];
    int tid = threadIdx.x;
    int base = tid * 16;
    int loc[16];
    int s = 0;
    for (int j = 0; j < 16; ++j) { loc[j] = s; s += c[base + j]; }
    part[tid] = s;
    __syncthreads();
    if (tid == 0) {
        int acc = 0;
        for (int i = 0; i < 256; ++i) { int v = part[i]; part[i] = acc; acc += v; }
    }
    __syncthreads();
    int b = part[tid];
    for (int j = 0; j < 16; ++j) { int v = b + loc[j]; of[base + j] = v; cu[base + j] = v; }
    if (tid == 255) of[NN] = b + s;
}

__global__ void k_fill(const int* __restrict__ ei, int* cur,
                       unsigned short* csrT, unsigned short* csrS) {
    int e = blockIdx.x * 256 + threadIdx.x;
    int s = ei[e], t = ei[NE + e];
    int p = atomicAdd(&cur[t], 1);
    csrT[p] = (unsigned short)s;   // in-neighbor (source) list of t
    int q = atomicAdd(&cur[NN + s], 1);
    csrS[q] = (unsigned short)t;   // out-neighbor (target) list of s
}

// ---- lin1: ylr[i][t] = xc_i . W1l[t] (t<68) | xc_i . W1r[t-68] (t>=68) ----
// 8 nodes/block, thread = (node n, out-group tg of 32); weights L1/L2-hot.

__global__ __launch_bounds__(256) void k_lin1(
        const float* __restrict__ x, const float* __restrict__ pos,
        const float* __restrict__ W1l, const float* __restrict__ W1r,
        float* __restrict__ ylr) {
    __shared__ __align__(16) float xc[8][140];   // pad 140: 2-way-free banks
    int tid = threadIdx.x;
    int nb = blockIdx.x * 8;
    {
        const float4* x4 = (const float4*)x;
        int n = tid >> 5, cc = tid & 31;
        float4 v = x4[(nb + n) * 32 + cc];
        *(float4*)&xc[n][cc * 4] = v;
        if (tid < 16) {
            const float4* p4 = (const float4*)pos;
            int n2 = tid >> 1, c2 = tid & 1;
            float4 pv = p4[(nb + n2) * 2 + c2];
            *(float4*)&xc[n2][128 + c2 * 4] = pv;
        }
    }
    __syncthreads();
    int n = tid >> 5, tg = tid & 31;
    int t2 = tg + 64, t4 = tg + 128;
    const float4* w0 = (const float4*)(W1l + tg * 136);
    const float4* w1 = (const float4*)(W1l + (tg + 32) * 136);
    const float4* w2 = (const float4*)(t2 < 68 ? W1l + t2 * 136 : W1r + (t2 - 68) * 136);
    const float4* w3 = (const float4*)(W1r + (tg + 28) * 136);          // t3-68 = tg+28
    const float4* w4 = (const float4*)(t4 < 136 ? W1r + (t4 - 68) * 136 : W1r);
    float a0 = 0.f, a1 = 0.f, a2 = 0.f, a3 = 0.f, a4 = 0.f;
    for (int k4 = 0; k4 < 34; ++k4) {
        float4 xv = *(const float4*)&xc[n][k4 * 4];
        float4 b0 = w0[k4], b1 = w1[k4], b2 = w2[k4], b3 = w3[k4], b4 = w4[k4];
        a0 += xv.x * b0.x + xv.y * b0.y + xv.z * b0.z + xv.w * b0.w;
        a1 += xv.x * b1.x + xv.y * b1.y + xv.z * b1.z + xv.w * b1.w;
        a2 += xv.x * b2.x + xv.y * b2.y + xv.z * b2.z + xv.w * b2.w;
        a3 += xv.x * b3.x + xv.y * b3.y + xv.z * b3.z + xv.w * b3.w;
        a4 += xv.x * b4.x + xv.y * b4.y + xv.z * b4.z + xv.w * b4.w;
    }
    float* orow = ylr + (nb + n) * 136;
    orow[tg] = a0;
    orow[tg + 32] = a1;
    orow[t2] = a2;
    orow[tg + 96] = a3;
    if (t4 < 136) orow[t4] = a4;
}

// ---- gather1: h1 = relu(mean_nbr(y1) + b1 + r1), thread = (node, f4 col) ----

__global__ __launch_bounds__(256) void k_gather1(
        const int* __restrict__ off_tgt, const unsigned short* __restrict__ csrT,
        const float* __restrict__ ylr, const float* __restrict__ b1v,
        float* __restrict__ h1) {
    int idx = blockIdx.x * 256 + threadIdx.x;   // grid*256 == NN*17 exactly
    int i = idx / 17;
    int c = idx - i * 17;
    int bgn = off_tgt[i], end = off_tgt[i + 1];
    int d = end - bgn;
    float inv = 1.f / (float)(d > 0 ? d : 1);
    const float4* y4 = (const float4*)ylr;      // row stride 34 f4
    float4 a0 = make_float4(0.f, 0.f, 0.f, 0.f), a1 = a0, a2 = a0, a3 = a0;
    int p = bgn;
    for (; p + 4 <= end; p += 4) {
        int j0 = csrT[p], j1 = csrT[p + 1], j2 = csrT[p + 2], j3 = csrT[p + 3];
        add4(a0, y4[j0 * 34 + c]);
        add4(a1, y4[j1 * 34 + c]);
        add4(a2, y4[j2 * 34 + c]);
        add4(a3, y4[j3 * 34 + c]);
    }
    for (; p < end; ++p) add4(a0, y4[(int)csrT[p] * 34 + c]);
    add4(a0, a1); add4(a2, a3); add4(a0, a2);
    float4 b = ((const float4*)b1v)[c];
    float4 r = y4[i * 34 + 17 + c];
    float4 o;
    o.x = fmaxf(a0.x * inv + b.x + r.x, 0.f);
    o.y = fmaxf(a0.y * inv + b.y + r.y, 0.f);
    o.z = fmaxf(a0.z * inv + b.z + r.z, 0.f);
    o.w = fmaxf(a0.w * inv + b.w + r.w, 0.f);
    ((float4*)h1)[i * 17 + c] = o;
}

// ---- lin2: yr2[i] = [y2(36 incl 2 zero-pad) | r2(36 incl 2 zero-pad)] ----

__global__ __launch_bounds__(256) void k_lin2(
        const float* __restrict__ h1, const float* __restrict__ W2l,
        const float* __restrict__ W2r, float* __restrict__ yr2) {
    __shared__ __align__(16) float hh[8][76];
    int tid = threadIdx.x;
    int nb = blockIdx.x * 8;
    if (tid < 136) {
        int n = tid / 17, cc = tid - n * 17;
        float4 v = ((const float4*)h1)[(nb + n) * 17 + cc];
        *(float4*)&hh[n][cc * 4] = v;
    }
    __syncthreads();
    int n = tid >> 5, tg = tid & 31;
    int t1 = tg + 32, t2 = tg + 64;
    const float4* w0 = (const float4*)(tg < 34 ? W2l + tg * 68 : W2r + (tg - 34) * 68);
    const float4* w1 = (const float4*)(t1 < 34 ? W2l + t1 * 68 : W2r + (t1 - 34) * 68);
    const float4* w2 = (const float4*)(t2 < 68 ? W2r + (t2 - 34) * 68 : W2r);
    float a0 = 0.f, a1 = 0.f, a2 = 0.f;
    for (int k4 = 0; k4 < 17; ++k4) {
        float4 xv = *(const float4*)&hh[n][k4 * 4];
        float4 b0 = w0[k4], b1 = w1[k4], b2 = w2[k4];
        a0 += xv.x * b0.x + xv.y * b0.y + xv.z * b0.z + xv.w * b0.w;
        a1 += xv.x * b1.x + xv.y * b1.y + xv.z * b1.z + xv.w * b1.w;
        a2 += xv.x * b2.x + xv.y * b2.y + xv.z * b2.z + xv.w * b2.w;
    }
    float* orow = yr2 + (nb + n) * 72;
    orow[tg + (tg >= 34 ? 2 : 0)] = a0;            // t<34 -> [t], else [t+2]
    orow[t1 + (t1 >= 34 ? 2 : 0)] = a1;
    if (tg < 4) {
        orow[t2 + 2] = a2;
        orow[34 + (tg & 1) + ((tg >> 1) ? 36 : 0)] = 0.f;   // pads 34,35,70,71
    }
}

// --- angle + Ox + W-GEMM + hsync, wave per node (4/block) -------------------
// Gather of y2 (9 f4/row): lanes split as 7 neighbor-groups x 9 cols.

__global__ __launch_bounds__(256) void k_angle_hs(
        const int* __restrict__ off_tgt, const unsigned short* __restrict__ csrT,
        const float* __restrict__ yr2,
        const float* __restrict__ b2v, const float* __restrict__ Wa,
        const float* __restrict__ ba,
        const float* __restrict__ x, const float* __restrict__ W,
        const float* __restrict__ bias,
        float2* __restrict__ cs, float2* __restrict__ hs) {
    __shared__ __align__(16) float Wt[TD * TD];    // 64 KB swizzled transpose of W
    __shared__ float4 ps[4][64];
    __shared__ __align__(16) float ox[4][TD];
    __shared__ __align__(16) float b2p[36], Wap[36];
    int tid = threadIdx.x;
    int w = tid >> 6, l = tid & 63;
    int i = blockIdx.x * 4 + w;

    // stage W -> LDS (swizzled: Wt[k*TD + (f ^ (k&30))] = W[f][k])
    {
        const float4* W4 = (const float4*)W;
        #pragma unroll 4
        for (int r = 0; r < 16; ++r) {
            int v = r * 256 + tid;
            float4 wv = W4[v];
            int m = v * 4;
            int f = m >> 7;
            int k0 = m & 127;
            Wt[(k0    ) * TD + (f ^ ((k0    ) & 30))] = wv.x;
            Wt[(k0 + 1) * TD + (f ^ ((k0 + 1) & 30))] = wv.y;
            Wt[(k0 + 2) * TD + (f ^ ((k0 + 2) & 30))] = wv.z;
            Wt[(k0 + 3) * TD + (f ^ ((k0 + 3) & 30))] = wv.w;
        }
    }
    if (tid < 36) {
        b2p[tid] = (tid < 34) ? b2v[tid] : 0.f;
        Wap[tid] = (tid < 34) ? Wa[tid] : 0.f;
    }
    __syncthreads();

    // gather y2 over in-neighbors: 7 groups of 9 lanes, 4 rounds in flight
    int bgn = off_tgt[i], end = off_tgt[i + 1];
    int d = end - bgn;
    float inv = 1.f / (float)(d > 0 ? d : 1);
    int g = l / 9, c = l - g * 9;
    bool active = (l < 63);
    const float4* y4 = (const float4*)yr2;       // row stride 18 f4, row NN = 0
    float4 acc0 = make_float4(0.f, 0.f, 0.f, 0.f), acc1 = acc0;
    for (int base = bgn; base < end; base += 28) {
        int p0 = base + g, p1 = p0 + 7, p2 = p0 + 14, p3 = p0 + 21;
        int j0 = (active && p0 < end) ? (int)csrT[p0] : NN;
        int j1 = (active && p1 < end) ? (int)csrT[p1] : NN;
        int j2 = (active && p2 < end) ? (int)csrT[p2] : NN;
        int j3 = (active && p3 < end) ? (int)csrT[p3] : NN;
        float4 v0 = y4[j0 * 18 + c];
        float4 v1 = y4[j1 * 18 + c];
        float4 v2 = y4[j2 * 18 + c];
        float4 v3 = y4[j3 * 18 + c];
        add4(acc0, v0); add4(acc1, v1); add4(acc0, v2); add4(acc1, v3);
    }
    add4(acc0, acc1);
    ps[w][l] = acc0;
    __syncthreads();

    float vdot = 0.f;
    if (l < 9) {
        float4 s4 = ps[w][l];
        add4(s4, ps[w][l +  9]); add4(s4, ps[w][l + 18]); add4(s4, ps[w][l + 27]);
        add4(s4, ps[w][l + 36]); add4(s4, ps[w][l + 45]); add4(s4, ps[w][l + 54]);
        float4 b = *(const float4*)&b2p[4 * l];
        float4 r = y4[i * 18 + 9 + l];
        float4 h2;
        h2.x = fmaxf(s4.x * inv + b.x + r.x, 0.f);
        h2.y = fmaxf(s4.y * inv + b.y + r.y, 0.f);
        h2.z = fmaxf(s4.z * inv + b.z + r.z, 0.f);
        h2.w = fmaxf(s4.w * inv + b.w + r.w, 0.f);
        float4 wa = *(const float4*)&Wap[4 * l];
        vdot = wa.x * h2.x + wa.y * h2.y + wa.z * h2.z + wa.w * h2.w;
    }
    for (int off = 32; off >= 1; off >>= 1) vdot += __shfl_xor(vdot, off);
    float ang = vdot + ba[0];
    float cc = cosf(ang), ss = sinf(ang);
    if (l == 0) cs[i] = make_float2(cc, ss);

    // Ox: lane l owns column pair (2l, 2l+1)
    int f0 = 2 * l, f1 = f0 + 1;
    float2 xv = *(const float2*)&x[i * TD + f0];
    ox[w][f0] = cc * xv.x - ss * xv.y;
    ox[w][f1] = ss * xv.x + cc * xv.y;
    __syncthreads();

    // GEMM from LDS
    float a0 = 0.f, a1 = 0.f;
    #pragma unroll 4
    for (int k = 0; k < TD; k += 2) {
        int sw = k & 30;
        float2 o2 = *(const float2*)&ox[w][k];
        float2 wA = *(const float2*)&Wt[k * TD + (f0 ^ sw)];
        float2 wB = *(const float2*)&Wt[(k + 1) * TD + (f0 ^ sw)];
        a0 += wA.x * o2.x + wB.x * o2.y;
        a1 += wA.y * o2.x + wB.y * o2.y;
    }
    float t0 = cc * a0 + ss * a1 + bias[f0];
    float t1 = -ss * a0 + cc * a1 + bias[f1];
    float u0 = cc * t0 - ss * t1;
    float u1 = ss * t0 + cc * t1;
    hs[i * 64 + l] = make_float2(u0, u1);
}

// ---- one Taylor step: wave = node row; half-wave = neighbor parity --------
// unroll 8: 8 float4 loads in flight per lane; pad row NN makes tails free.
// MODE: 1 = first step (init res), 0 = middle, 2 = last (fuse O^T + relu)

template <int MODE>
__global__ __launch_bounds__(256) void k_step(
        const float4* __restrict__ tin, float4* __restrict__ tout,
        float4* __restrict__ res, const int* __restrict__ off_src,
        const unsigned short* __restrict__ csrS, float scale,
        const float2* __restrict__ cs, float4* __restrict__ outv) {
    int idx = blockIdx.x * 256 + threadIdx.x;
    int i = idx >> 6;          // node (wave-uniform)
    int l = idx & 63;
    int c32 = l & 31;          // float4 column block
    int hi = l >> 5;           // neighbor parity
    int bgn = off_src[i], end = off_src[i + 1];
    int d = end - bgn;
    float dinv = d > 0 ? 1.f / (float)d : 0.f;
    float4 u = tin[i * 32 + c32];
    float4 acc0 = make_float4(0.f, 0.f, 0.f, 0.f);
    float4 acc1 = acc0, acc2 = acc0, acc3 = acc0;
    for (int base = bgn; base < end; base += 64) {
        int m = end - base;
        if (m > 64) m = 64;
        int jj = (l < m) ? (int)csrS[base + l] : NN;   // pad -> zero row
        int pr = (((m + 1) >> 1) + 7) & ~7;            // round pairs to 8
        for (int q = 0; q < pr; q += 8) {
            int j0 = __shfl(jj, 2 * q + hi);
            int j1 = __shfl(jj, 2 * q + 2 + hi);
            int j2 = __shfl(jj, 2 * q + 4 + hi);
            int j3 = __shfl(jj, 2 * q + 6 + hi);
            int j4 = __shfl(jj, 2 * q + 8 + hi);
            int j5 = __shfl(jj, 2 * q + 10 + hi);
            int j6 = __shfl(jj, 2 * q + 12 + hi);
            int j7 = __shfl(jj, 2 * q + 14 + hi);
            float4 v0 = tin[j0 * 32 + c32];
            float4 v1 = tin[j1 * 32 + c32];
            float4 v2 = tin[j2 * 32 + c32];
            float4 v3 = tin[j3 * 32 + c32];
            float4 v4 = tin[j4 * 32 + c32];
            float4 v5 = tin[j5 * 32 + c32];
            float4 v6 = tin[j6 * 32 + c32];
            float4 v7 = tin[j7 * 32 + c32];
            add4(acc0, v0); add4(acc1, v1); add4(acc2, v2); add4(acc3, v3);
            add4(acc0, v4); add4(acc1, v5); add4(acc2, v6); add4(acc3, v7);
        }
    }
    add4(acc0, acc1); add4(acc2, acc3); add4(acc0, acc2);
    acc0.x += __shfl_xor(acc0.x, 32);
    acc0.y += __shfl_xor(acc0.y, 32);
    acc0.z += __shfl_xor(acc0.z, 32);
    acc0.w += __shfl_xor(acc0.w, 32);
    if (hi == 0) {
        float4 nu;
        nu.x = scale * (u.x - dinv * acc0.x);
        nu.y = scale * (u.y - dinv * acc0.y);
        nu.z = scale * (u.z - dinv * acc0.z);
        nu.w = scale * (u.w - dinv * acc0.w);
        if (MODE == 1) {
            res[i * 32 + c32] = make_float4(u.x + nu.x, u.y + nu.y,
                                            u.z + nu.z, u.w + nu.w);
            tout[i * 32 + c32] = nu;
        } else if (MODE == 0) {
            float4 r = res[i * 32 + c32];
            add4(r, nu);
            res[i * 32 + c32] = r;
            tout[i * 32 + c32] = nu;
        } else {
            float4 r = res[i * 32 + c32];
            add4(r, nu);
            float2 cv = cs[i];
            float o0 =  cv.x * r.x + cv.y * r.y;
            float o1 = -cv.y * r.x + cv.x * r.y;
            float o2 =  cv.x * r.z + cv.y * r.w;
            float o3 = -cv.y * r.z + cv.x * r.w;
            outv[i * 32 + c32] = make_float4(fmaxf(o0, 0.f), fmaxf(o1, 0.f),
                                             fmaxf(o2, 0.f), fmaxf(o3, 0.f));
        }
    }
}

extern "C" void kernel_launch(void* const* d_in, const int* in_sizes, int n_in,
                              void* d_out, int out_size, void* d_ws, size_t ws_size,
                              hipStream_t stream) {
    const float* x    = (const float*)d_in[0];
    const float* pos  = (const float*)d_in[1];
    const int*   ei   = (const int*)d_in[2];
    const float* W1l  = (const float*)d_in[3];
    const float* b1   = (const float*)d_in[4];
    const float* W1r  = (const float*)d_in[5];
    const float* W2l  = (const float*)d_in[6];
    const float* b2   = (const float*)d_in[7];
    const float* W2r  = (const float*)d_in[8];
    const float* Wa   = (const float*)d_in[9];
    const float* ba   = (const float*)d_in[10];
    const float* W    = (const float*)d_in[11];
    const float* bias = (const float*)d_in[12];
    float4* out = (float4*)d_out;

    char* ws = (char*)d_ws;
    size_t o = 0;
    auto alloc = [&](size_t bytes) -> void* {
        void* p = ws + o;
        o += (bytes + 255) & ~(size_t)255;
        return p;
    };

    int* cnt  = (int*)alloc(2 * NN * 4);          // [tgt | src]
    int* off  = (int*)alloc(2 * (NN + 1) * 4);    // [off_tgt | off_src]
    int* cur  = (int*)alloc(2 * NN * 4);
    unsigned short* csrT = (unsigned short*)alloc(NE * 2);
    unsigned short* csrS = (unsigned short*)alloc(NE * 2);
    float* ylr  = (float*)alloc(NN * 136 * 4);          // [y1(68) | r1(68)]
    float* h1   = (float*)alloc(NN * HD1 * 4);
    float* yr2  = (float*)alloc((NN + 1) * 72 * 4);     // [y2(36) | r2(36)], row NN = 0
    float2* cs  = (float2*)alloc(NN * 8);
    float2* hs  = (float2*)alloc((NN * 64 + 64) * 8);   // +1 zero row
    float4* ta  = (float4*)alloc((NN * 64 + 64) * 8);   // +1 zero row
    float4* tb  = (float4*)alloc((NN * 64 + 64) * 8);   // +1 zero row
    float4* res = (float4*)alloc(NN * 64 * 8);

    int* off_tgt = off;
    int* off_src = off + (NN + 1);

    hipMemsetAsync(cnt, 0, 2 * NN * 4, stream);
    k_count<<<NE / 256, 256, 0, stream>>>(ei, cnt, hs, (float2*)ta, (float2*)tb,
                                          (float4*)yr2);
    k_scan2<<<2, 256, 0, stream>>>(cnt, off, cur);
    k_fill<<<NE / 256, 256, 0, stream>>>(ei, cur, csrT, csrS);

    k_lin1<<<NN / 8, 256, 0, stream>>>(x, pos, W1l, W1r, ylr);
    k_gather1<<<NN * 17 / 256, 256, 0, stream>>>(off_tgt, csrT, ylr, b1, h1);
    k_lin2<<<NN / 8, 256, 0, stream>>>(h1, W2l, W2r, yr2);
    k_angle_hs<<<NN / 4, 256, 0, stream>>>(off_tgt, csrT, yr2, b2, Wa, ba,
                                           x, W, bias, cs, hs);

    const int G = NN * 64 / 256;   // 1024 blocks
    k_step<1><<<G, 256, 0, stream>>>((const float4*)hs, ta, res, off_src, csrS, -1.f / 1.f, cs, out);
    k_step<0><<<G, 256, 0, stream>>>(ta, tb, res, off_src, csrS, -1.f / 2.f, cs, out);
    k_step<0><<<G, 256, 0, stream>>>(tb, ta, res, off_src, csrS, -1.f / 3.f, cs, out);
    k_step<0><<<G, 256, 0, stream>>>(ta, tb, res, off_src, csrS, -1.f / 4.f, cs, out);
    k_step<0><<<G, 256, 0, stream>>>(tb, ta, res, off_src, csrS, -1.f / 5.f, cs, out);
    k_step<0><<<G, 256, 0, stream>>>(ta, tb, res, off_src, csrS, -1.f / 6.f, cs, out);
    k_step<0><<<G, 256, 0, stream>>>(tb, ta, res, off_src, csrS, -1.f / 7.f, cs, out);
    k_step<2><<<G, 256, 0, stream>>>(ta, tb, res, off_src, csrS, -1.f / 8.f, cs, out);
}